// Round 1
// baseline (492.911 us; speedup 1.0000x reference)
//
#include <hip/hip_runtime.h>
#include <hip/hip_bf16.h>

// Problem constants (B,S,D,H,KVH,HD) = (2,2048,2048,16,8,128)
#define B_   2
#define S_   2048
#define D_   2048
#define H_   16
#define KVH_ 8
#define HD_  128
#define TOK_ (B_ * S_)        // 4096 rows
#define SCALE_ 0.08838834764831845f   // 1/sqrt(128)

typedef __bf16 bf16_t;
typedef bf16_t bf16x8 __attribute__((ext_vector_type(8)));
typedef bf16_t bf16x4 __attribute__((ext_vector_type(4)));
typedef float  f32x4  __attribute__((ext_vector_type(4)));

// ---------------------------------------------------------------- cvt f32->bf16
__global__ __launch_bounds__(256) void cvt_bf16(const float* __restrict__ in,
                                                bf16_t* __restrict__ out, int n) {
    int i = (blockIdx.x * 256 + threadIdx.x) * 4;
    if (i < n) {
        float4 v = *(const float4*)(in + i);
        bf16x4 o;
        o[0] = (bf16_t)v.x; o[1] = (bf16_t)v.y; o[2] = (bf16_t)v.z; o[3] = (bf16_t)v.w;
        *(bf16x4*)(out + i) = o;
    }
}

// ---------------------------------------------------------------- GEMM C = A * B^T
// A [M][K] bf16, Bm [N][K] bf16, C [M][N] OutT.  M,N % 128 == 0, K % 32 == 0.
template <typename OutT>
__global__ __launch_bounds__(256) void gemm_bt(const bf16_t* __restrict__ A,
                                               const bf16_t* __restrict__ Bm,
                                               OutT* __restrict__ C,
                                               int M, int N, int K) {
    __shared__ bf16_t As[128][40];   // +8 pad: 80B row stride -> ~2-way banks
    __shared__ bf16_t Bs[128][40];
    int tid = threadIdx.x;
    int w = tid >> 6, l = tid & 63;
    int lr = l & 15, lk = l >> 4;
    int wr = (w >> 1) * 64, wc = (w & 1) * 64;
    int m0 = blockIdx.y * 128, n0 = blockIdx.x * 128;

    f32x4 acc[4][4] = {};
    int sr = tid >> 2, sc = (tid & 3) * 8;   // staging: row tid/4 (+64), col chunk
    int nk = K >> 5;
    for (int kt = 0; kt < nk; ++kt) {
        int k0 = kt * 32;
        *(uint4*)&As[sr][sc]      = *(const uint4*)&A[(size_t)(m0 + sr) * K + k0 + sc];
        *(uint4*)&As[sr + 64][sc] = *(const uint4*)&A[(size_t)(m0 + sr + 64) * K + k0 + sc];
        *(uint4*)&Bs[sr][sc]      = *(const uint4*)&Bm[(size_t)(n0 + sr) * K + k0 + sc];
        *(uint4*)&Bs[sr + 64][sc] = *(const uint4*)&Bm[(size_t)(n0 + sr + 64) * K + k0 + sc];
        __syncthreads();
        bf16x8 af[4], bfr[4];
#pragma unroll
        for (int mm = 0; mm < 4; ++mm) af[mm]  = *(const bf16x8*)&As[wr + mm * 16 + lr][lk * 8];
#pragma unroll
        for (int nn = 0; nn < 4; ++nn) bfr[nn] = *(const bf16x8*)&Bs[wc + nn * 16 + lr][lk * 8];
#pragma unroll
        for (int mm = 0; mm < 4; ++mm)
#pragma unroll
            for (int nn = 0; nn < 4; ++nn)
                acc[mm][nn] = __builtin_amdgcn_mfma_f32_16x16x32_bf16(af[mm], bfr[nn], acc[mm][nn], 0, 0, 0);
        __syncthreads();
    }
#pragma unroll
    for (int mm = 0; mm < 4; ++mm)
#pragma unroll
        for (int nn = 0; nn < 4; ++nn)
#pragma unroll
            for (int i = 0; i < 4; ++i) {
                int r = m0 + wr + mm * 16 + lk * 4 + i;
                int c = n0 + wc + nn * 16 + lr;
                C[(size_t)r * N + c] = (OutT)acc[mm][nn][i];
            }
}

// ---------------------------------------------------------------- RMSNorm + RoPE
// in : [b][s][nh][128] bf16 (GEMM output rows), out: [b][nh][s][128] bf16 head-major
__global__ __launch_bounds__(256) void rope_norm(const bf16_t* __restrict__ in,
                                                 const float* __restrict__ nw,
                                                 bf16_t* __restrict__ out, int nh) {
    int row = blockIdx.x * 4 + (threadIdx.x >> 6);
    int l = threadIdx.x & 63;
    int h = row % nh;
    int s = (row / nh) % S_;
    int b = row / (nh * S_);
    const bf16_t* src = in + (size_t)row * HD_;
    float q0 = (float)src[l], q1 = (float)src[64 + l];
    float ss = q0 * q0 + q1 * q1;
#pragma unroll
    for (int off = 1; off < 64; off <<= 1) ss += __shfl_xor(ss, off);
    float rms = rsqrtf(ss * (1.0f / 128.0f) + 1e-6f);
    float qn0 = q0 * rms * nw[l];
    float qn1 = q1 * rms * nw[64 + l];
    // inv_freq = 10000^(-l/64) = exp2(-l * log2(10000)/64)
    float invf = exp2f(-(float)l * 0.20762050593046013f);
    float ang = (float)s * invf;
    float si, c;
    sincosf(ang, &si, &c);
    float o0 = qn0 * c - qn1 * si;
    float o1 = qn1 * c + qn0 * si;
    bf16_t* dst = out + (((size_t)(b * nh + h)) * S_ + s) * HD_;
    dst[l]      = (bf16_t)o0;
    dst[64 + l] = (bf16_t)o1;
}

// ---------------------------------------------------------------- V transpose
// vproj [b][s][kvh][128] -> vt [b][kvh][128][S]
__global__ __launch_bounds__(256) void transpose_v(const bf16_t* __restrict__ vproj,
                                                   bf16_t* __restrict__ vt) {
    __shared__ bf16_t tile[32][33];
    int bk = blockIdx.z;            // b*KVH + kvh
    int b = bk >> 3, kvh = bk & 7;
    int s0 = blockIdx.x * 32, d0 = blockIdx.y * 32;
    int tx = threadIdx.x, ty = threadIdx.y;   // 32 x 8
#pragma unroll
    for (int j = 0; j < 4; ++j) {
        int s = s0 + ty + j * 8;
        tile[ty + j * 8][tx] = vproj[((size_t)(b * S_ + s) * KVH_ + kvh) * HD_ + d0 + tx];
    }
    __syncthreads();
#pragma unroll
    for (int j = 0; j < 4; ++j) {
        int d = d0 + ty + j * 8;
        vt[((size_t)(b * KVH_ + kvh) * HD_ + d) * S_ + s0 + tx] = tile[tx][ty + j * 8];
    }
}

// ---------------------------------------------------------------- flash attention
// qh [b][H][S][128], kh [b][KVH][S][128], vt [b][KVH][128][S] (all bf16)
// out [b][s][H][128] bf16.  QBLK=64 (4 waves x 16 rows), KBLK=32, causal.
__global__ __launch_bounds__(256) void attn_fwd(const bf16_t* __restrict__ qh,
                                                const bf16_t* __restrict__ kh,
                                                const bf16_t* __restrict__ vt,
                                                bf16_t* __restrict__ out) {
    int qt = blockIdx.x;          // 0..31
    int bh = blockIdx.y;          // 0..31
    int b = bh >> 4, h = bh & 15;
    int kvh = h >> 1;
    int tid = threadIdx.x, w = tid >> 6, l = tid & 63;
    int lr = l & 15, lk = l >> 4;
    int q0 = qt * 64;

    __shared__ bf16_t Ks[32][136];    // +8 pad
    __shared__ bf16_t Vs[128][40];    // +8 pad
    __shared__ bf16_t Ps[4][16][40];  // per-wave P transpose buffer

    const bf16_t* qbase = qh + ((size_t)(b * H_ + h) * S_ + q0 + w * 16) * HD_;
    const bf16_t* kbase = kh + ((size_t)(b * KVH_ + kvh) * S_) * HD_;
    const bf16_t* vbase = vt + ((size_t)(b * KVH_ + kvh) * HD_) * S_;

    bf16x8 qf[4];
#pragma unroll
    for (int c = 0; c < 4; ++c)
        qf[c] = *(const bf16x8*)(qbase + (size_t)lr * HD_ + c * 32 + lk * 8);

    f32x4 acc[8] = {};
    float m_i[4], l_i[4];
#pragma unroll
    for (int i = 0; i < 4; ++i) { m_i[i] = -__builtin_inff(); l_i[i] = 0.f; }

    int skr = tid >> 4, skc = (tid & 15) * 8;   // K staging: 16 rows / pass
    int svr = tid >> 2, svc = (tid & 3) * 8;    // V staging: 64 rows / pass
    int nkt = (q0 + 64) >> 5;

    for (int kt = 0; kt < nkt; ++kt) {
        int k0 = kt * 32;
        *(uint4*)&Ks[skr][skc]      = *(const uint4*)&kbase[(size_t)(k0 + skr) * HD_ + skc];
        *(uint4*)&Ks[skr + 16][skc] = *(const uint4*)&kbase[(size_t)(k0 + skr + 16) * HD_ + skc];
        *(uint4*)&Vs[svr][svc]      = *(const uint4*)&vbase[(size_t)svr * S_ + k0 + svc];
        *(uint4*)&Vs[svr + 64][svc] = *(const uint4*)&vbase[(size_t)(svr + 64) * S_ + k0 + svc];
        __syncthreads();

        // QK^T : scores S[q=lk*4+i][k=n*16+lr]
        f32x4 scq[2] = {};
#pragma unroll
        for (int n = 0; n < 2; ++n)
#pragma unroll
            for (int c = 0; c < 4; ++c) {
                bf16x8 kf = *(const bf16x8*)&Ks[n * 16 + lr][c * 32 + lk * 8];
                scq[n] = __builtin_amdgcn_mfma_f32_16x16x32_bf16(qf[c], kf, scq[n], 0, 0, 0);
            }

        // online softmax
        float p0v[4], p1v[4], alpha[4];
#pragma unroll
        for (int i = 0; i < 4; ++i) {
            int grow = q0 + w * 16 + lk * 4 + i;
            float v0 = scq[0][i] * SCALE_; if (k0 + lr > grow)      v0 = -__builtin_inff();
            float v1 = scq[1][i] * SCALE_; if (k0 + 16 + lr > grow) v1 = -__builtin_inff();
            float mx = fmaxf(v0, v1);
            mx = fmaxf(mx, __shfl_xor(mx, 1));
            mx = fmaxf(mx, __shfl_xor(mx, 2));
            mx = fmaxf(mx, __shfl_xor(mx, 4));
            mx = fmaxf(mx, __shfl_xor(mx, 8));
            float mnew = fmaxf(m_i[i], mx);
            float a  = __expf(m_i[i] - mnew);
            float p0 = __expf(v0 - mnew);
            float p1 = __expf(v1 - mnew);
            float rs = p0 + p1;
            rs += __shfl_xor(rs, 1);
            rs += __shfl_xor(rs, 2);
            rs += __shfl_xor(rs, 4);
            rs += __shfl_xor(rs, 8);
            l_i[i] = l_i[i] * a + rs;
            m_i[i] = mnew;
            alpha[i] = a;
            p0v[i] = p0; p1v[i] = p1;
        }
#pragma unroll
        for (int dt = 0; dt < 8; ++dt)
#pragma unroll
            for (int i = 0; i < 4; ++i) acc[dt][i] *= alpha[i];

        // P -> per-wave LDS (transpose to A-frag layout)
#pragma unroll
        for (int i = 0; i < 4; ++i) {
            Ps[w][lk * 4 + i][lr]      = (bf16_t)p0v[i];
            Ps[w][lk * 4 + i][16 + lr] = (bf16_t)p1v[i];
        }
        bf16x8 pf = *(const bf16x8*)&Ps[w][lr][lk * 8];

        // PV
#pragma unroll
        for (int dt = 0; dt < 8; ++dt) {
            bf16x8 vf = *(const bf16x8*)&Vs[dt * 16 + lr][lk * 8];
            acc[dt] = __builtin_amdgcn_mfma_f32_16x16x32_bf16(pf, vf, acc[dt], 0, 0, 0);
        }
        __syncthreads();
    }

    // epilogue: out[b][s][h][d]
#pragma unroll
    for (int dt = 0; dt < 8; ++dt)
#pragma unroll
        for (int i = 0; i < 4; ++i) {
            int s = q0 + w * 16 + lk * 4 + i;
            out[(((size_t)b * S_ + s) * H_ + h) * HD_ + dt * 16 + lr] =
                (bf16_t)(acc[dt][i] / l_i[i]);
        }
}

// ---------------------------------------------------------------- launch
extern "C" void kernel_launch(void* const* d_in, const int* in_sizes, int n_in,
                              void* d_out, int out_size, void* d_ws, size_t ws_size,
                              hipStream_t stream) {
    const float* x   = (const float*)d_in[0];
    const float* Wq  = (const float*)d_in[1];
    const float* Wk  = (const float*)d_in[2];
    const float* Wv  = (const float*)d_in[3];
    const float* Wo  = (const float*)d_in[4];
    const float* qnw = (const float*)d_in[5];
    const float* knw = (const float*)d_in[6];
    float* outp = (float*)d_out;

    char* ws = (char*)d_ws;
    size_t off = 0;
    auto alloc = [&](size_t bytes) -> void* {
        void* p = ws + off;
        off += (bytes + 255) & ~(size_t)255;
        return p;
    };
    bf16_t* xb    = (bf16_t*)alloc((size_t)TOK_ * D_ * 2);
    bf16_t* wqb   = (bf16_t*)alloc((size_t)D_ * D_ * 2);
    bf16_t* wkb   = (bf16_t*)alloc((size_t)KVH_ * HD_ * D_ * 2);
    bf16_t* wvb   = (bf16_t*)alloc((size_t)KVH_ * HD_ * D_ * 2);
    bf16_t* wob   = (bf16_t*)alloc((size_t)D_ * D_ * 2);
    bf16_t* qproj = (bf16_t*)alloc((size_t)TOK_ * D_ * 2);
    bf16_t* kproj = (bf16_t*)alloc((size_t)TOK_ * KVH_ * HD_ * 2);
    bf16_t* vproj = (bf16_t*)alloc((size_t)TOK_ * KVH_ * HD_ * 2);
    bf16_t* qhm   = (bf16_t*)alloc((size_t)TOK_ * D_ * 2);
    bf16_t* khm   = (bf16_t*)alloc((size_t)TOK_ * KVH_ * HD_ * 2);
    bf16_t* vtm   = (bf16_t*)alloc((size_t)TOK_ * KVH_ * HD_ * 2);
    bf16_t* attn  = (bf16_t*)alloc((size_t)TOK_ * D_ * 2);
    (void)ws_size; (void)in_sizes; (void)n_in; (void)out_size;

    // converts
    cvt_bf16<<<(TOK_ * D_) / 1024, 256, 0, stream>>>(x, xb, TOK_ * D_);
    cvt_bf16<<<(D_ * D_) / 1024, 256, 0, stream>>>(Wq, wqb, D_ * D_);
    cvt_bf16<<<(KVH_ * HD_ * D_) / 1024, 256, 0, stream>>>(Wk, wkb, KVH_ * HD_ * D_);
    cvt_bf16<<<(KVH_ * HD_ * D_) / 1024, 256, 0, stream>>>(Wv, wvb, KVH_ * HD_ * D_);
    cvt_bf16<<<(D_ * D_) / 1024, 256, 0, stream>>>(Wo, wob, D_ * D_);

    // projections
    gemm_bt<bf16_t><<<dim3(D_ / 128, TOK_ / 128), 256, 0, stream>>>(xb, wqb, qproj, TOK_, D_, D_);
    gemm_bt<bf16_t><<<dim3((KVH_ * HD_) / 128, TOK_ / 128), 256, 0, stream>>>(xb, wkb, kproj, TOK_, KVH_ * HD_, D_);
    gemm_bt<bf16_t><<<dim3((KVH_ * HD_) / 128, TOK_ / 128), 256, 0, stream>>>(xb, wvb, vproj, TOK_, KVH_ * HD_, D_);

    // norm + rope -> head-major
    rope_norm<<<(B_ * S_ * H_) / 4, 256, 0, stream>>>(qproj, qnw, qhm, H_);
    rope_norm<<<(B_ * S_ * KVH_) / 4, 256, 0, stream>>>(kproj, knw, khm, KVH_);

    // V transpose
    transpose_v<<<dim3(S_ / 32, HD_ / 32, B_ * KVH_), dim3(32, 8), 0, stream>>>(vproj, vtm);

    // attention
    attn_fwd<<<dim3(S_ / 64, B_ * H_), 256, 0, stream>>>(qhm, khm, vtm, attn);

    // output projection (f32 out)
    gemm_bt<float><<<dim3(D_ / 128, TOK_ / 128), 256, 0, stream>>>(attn, wob, outp, TOK_, D_, D_);
}

// Round 2
// 390.277 us; speedup vs baseline: 1.2630x; 1.2630x over previous
//
#include <hip/hip_runtime.h>
#include <hip/hip_bf16.h>

// Problem constants (B,S,D,H,KVH,HD) = (2,2048,2048,16,8,128)
#define B_   2
#define S_   2048
#define D_   2048
#define H_   16
#define KVH_ 8
#define HD_  128
#define TOK_ (B_ * S_)        // 4096 rows
#define SCALE_LOG2E_ (0.08838834764831845f * 1.4426950408889634f)

typedef __bf16 bf16_t;
typedef bf16_t bf16x8 __attribute__((ext_vector_type(8)));
typedef bf16_t bf16x4 __attribute__((ext_vector_type(4)));
typedef float  f32x4  __attribute__((ext_vector_type(4)));

#if __has_builtin(__builtin_amdgcn_exp2f)
#define EXP2F(x) __builtin_amdgcn_exp2f(x)
#else
#define EXP2F(x) exp2f(x)
#endif

// async global->LDS, 16B per lane (dest must be wave-uniform base + lane*16)
__device__ __forceinline__ void gload16(const bf16_t* g, bf16_t* l) {
    auto* gp = (const __attribute__((address_space(1))) unsigned int*)(g);
    auto* lp = (__attribute__((address_space(3))) unsigned int*)(l);
    __builtin_amdgcn_global_load_lds(gp, lp, 16, 0, 0);
}

// ---------------------------------------------------------------- cvt f32->bf16
__global__ __launch_bounds__(256) void cvt_bf16(const float* __restrict__ in,
                                                bf16_t* __restrict__ out, int n) {
    int i = (blockIdx.x * 256 + threadIdx.x) * 4;
    if (i < n) {
        float4 v = *(const float4*)(in + i);
        bf16x4 o;
        o[0] = (bf16_t)v.x; o[1] = (bf16_t)v.y; o[2] = (bf16_t)v.z; o[3] = (bf16_t)v.w;
        *(bf16x4*)(out + i) = o;
    }
}

// ---------------------------------------------------------------- GEMM C = A * B^T
// m97 structure: linear LDS [128][32], global_load_lds width=16 staging.
template <typename OutT>
__global__ __launch_bounds__(256) void gemm_bt(const bf16_t* __restrict__ A,
                                               const bf16_t* __restrict__ Bm,
                                               OutT* __restrict__ C,
                                               int M, int N, int K) {
    __shared__ bf16_t As[128 * 32];
    __shared__ bf16_t Bs[128 * 32];
    int tid = threadIdx.x;
    int w = tid >> 6, l = tid & 63;
    int lr = l & 15, lk = l >> 4;
    int wr = (w >> 1) * 64, wc = (w & 1) * 64;
    int m0 = blockIdx.y * 128, n0 = blockIdx.x * 128;

    int srow = tid >> 2, scol = (tid & 3) * 8;
    f32x4 acc[4][4] = {};
    int nk = K >> 5;
    for (int kt = 0; kt < nk; ++kt) {
        int k0 = kt * 32;
        gload16(&A[(size_t)(m0 + srow) * K + k0 + scol],       &As[tid * 8]);
        gload16(&A[(size_t)(m0 + 64 + srow) * K + k0 + scol],  &As[2048 + tid * 8]);
        gload16(&Bm[(size_t)(n0 + srow) * K + k0 + scol],      &Bs[tid * 8]);
        gload16(&Bm[(size_t)(n0 + 64 + srow) * K + k0 + scol], &Bs[2048 + tid * 8]);
        __syncthreads();
        bf16x8 af[4], bfr[4];
#pragma unroll
        for (int mm = 0; mm < 4; ++mm) af[mm]  = *(const bf16x8*)&As[(wr + mm * 16 + lr) * 32 + lk * 8];
#pragma unroll
        for (int nn = 0; nn < 4; ++nn) bfr[nn] = *(const bf16x8*)&Bs[(wc + nn * 16 + lr) * 32 + lk * 8];
#pragma unroll
        for (int mm = 0; mm < 4; ++mm)
#pragma unroll
            for (int nn = 0; nn < 4; ++nn)
                acc[mm][nn] = __builtin_amdgcn_mfma_f32_16x16x32_bf16(af[mm], bfr[nn], acc[mm][nn], 0, 0, 0);
        __syncthreads();
    }
#pragma unroll
    for (int mm = 0; mm < 4; ++mm)
#pragma unroll
        for (int nn = 0; nn < 4; ++nn)
#pragma unroll
            for (int i = 0; i < 4; ++i) {
                int r = m0 + wr + mm * 16 + lk * 4 + i;
                int c = n0 + wc + nn * 16 + lr;
                C[(size_t)r * N + c] = (OutT)acc[mm][nn][i];
            }
}

// ---------------------------------------------------------------- RMSNorm + RoPE
// in: rows [b][s][row_heads*128], uses heads [head_off, head_off+nh)
// out: [b][nh][s][128] bf16 head-major, scaled by `scale`
__global__ __launch_bounds__(256) void rope_norm(const bf16_t* __restrict__ in,
                                                 const float* __restrict__ nw,
                                                 bf16_t* __restrict__ out,
                                                 int nh, int row_heads, int head_off,
                                                 float scale) {
    int row = blockIdx.x * 4 + (threadIdx.x >> 6);
    int l = threadIdx.x & 63;
    int h = row % nh;
    int s = (row / nh) % S_;
    int b = row / (nh * S_);
    const bf16_t* src = in + ((size_t)(b * S_ + s) * row_heads + head_off + h) * HD_;
    float q0 = (float)src[l], q1 = (float)src[64 + l];
    float ss = q0 * q0 + q1 * q1;
#pragma unroll
    for (int off = 1; off < 64; off <<= 1) ss += __shfl_xor(ss, off);
    float rms = rsqrtf(ss * (1.0f / 128.0f) + 1e-6f);
    float qn0 = q0 * rms * nw[l];
    float qn1 = q1 * rms * nw[64 + l];
    float invf = exp2f(-(float)l * 0.20762050593046013f);
    float ang = (float)s * invf;
    float si, c;
    sincosf(ang, &si, &c);
    float o0 = (qn0 * c - qn1 * si) * scale;
    float o1 = (qn1 * c + qn0 * si) * scale;
    bf16_t* dst = out + (((size_t)(b * nh + h)) * S_ + s) * HD_;
    dst[l]      = (bf16_t)o0;
    dst[64 + l] = (bf16_t)o1;
}

// ---------------------------------------------------------------- V transpose
// kvproj [b][s][16*128] (V heads at offset 8) -> vt [b][kvh][128][S]
__global__ __launch_bounds__(256) void transpose_v(const bf16_t* __restrict__ kvproj,
                                                   bf16_t* __restrict__ vt) {
    __shared__ bf16_t tile[32][33];
    int bk = blockIdx.z;            // b*KVH + kvh
    int b = bk >> 3, kvh = bk & 7;
    int s0 = blockIdx.x * 32, d0 = blockIdx.y * 32;
    int tx = threadIdx.x, ty = threadIdx.y;   // 32 x 8
#pragma unroll
    for (int j = 0; j < 4; ++j) {
        int s = s0 + ty + j * 8;
        tile[ty + j * 8][tx] = kvproj[((size_t)(b * S_ + s) * 16 + 8 + kvh) * HD_ + d0 + tx];
    }
    __syncthreads();
#pragma unroll
    for (int j = 0; j < 4; ++j) {
        int d = d0 + ty + j * 8;
        vt[((size_t)(b * KVH_ + kvh) * HD_ + d) * S_ + s0 + tx] = tile[tx][ty + j * 8];
    }
}

// ---------------------------------------------------------------- flash attention
// qh [b][H][S][128] (pre-scaled by SCALE*log2e), kh [b][KVH][S][128],
// vt [b][KVH][128][S], out [b][s][H][128] bf16.
// QBLK=64 (4 waves x 16 rows), KBLK=64, causal, log2-domain online softmax.
__global__ __launch_bounds__(256) void attn_fwd(const bf16_t* __restrict__ qh,
                                                const bf16_t* __restrict__ kh,
                                                const bf16_t* __restrict__ vt,
                                                bf16_t* __restrict__ out) {
    int qt = (S_ / 64 - 1) - blockIdx.x;      // longest blocks first
    int bh = blockIdx.y;
    int b = bh >> 4, h = bh & 15, kvh = h >> 1;
    int tid = threadIdx.x, w = tid >> 6, l = tid & 63;
    int lr = l & 15, lk = l >> 4;
    int q0 = qt * 64;
    int swz = (lr & 7) << 4;

    __shared__ bf16_t Ks[64 * 128];   // [64 k][128 d], XOR-swizzled rows
    __shared__ bf16_t Vs[128 * 64];   // [128 d][64 k], XOR-swizzled rows
    __shared__ bf16_t Ps[4][16 * 64]; // per-wave [16 q][64 k], XOR-swizzled

    const bf16_t* qbase = qh + ((size_t)(b * H_ + h) * S_ + q0 + w * 16) * HD_;
    const bf16_t* kbase = kh + ((size_t)(b * KVH_ + kvh) * S_) * HD_;
    const bf16_t* vbase = vt + ((size_t)(b * KVH_ + kvh) * HD_) * S_;

    bf16x8 qf[4];
#pragma unroll
    for (int c = 0; c < 4; ++c)
        qf[c] = *(const bf16x8*)(qbase + (size_t)lr * HD_ + c * 32 + lk * 8);

    f32x4 acc[8] = {};
    float m_i[4], l_i[4];
#pragma unroll
    for (int i = 0; i < 4; ++i) { m_i[i] = -3e38f; l_i[i] = 0.f; }

    int krow = tid >> 4, kch = tid & 15;   // K stage: 16 rows/pass x 16 chunks
    int vrow = tid >> 3, vch = tid & 7;    // V stage: 32 rows/pass x 8 chunks

    for (int kt = 0; kt <= qt; ++kt) {
        int k0 = kt * 64;
#pragma unroll
        for (int p = 0; p < 4; ++p) {
            int kr = krow + p * 16;
            *(bf16x8*)&Ks[kr * 128 + ((kch * 16) ^ ((kr & 7) << 4)) / 2] =
                *(const bf16x8*)&kbase[(size_t)(k0 + kr) * HD_ + kch * 8];
            int vr = vrow + p * 32;
            *(bf16x8*)&Vs[vr * 64 + ((vch * 16) ^ ((vr & 7) << 4)) / 2] =
                *(const bf16x8*)&vbase[(size_t)vr * S_ + k0 + vch * 8];
        }
        __syncthreads();

        // QK^T in log2 domain (scale folded into Q)
        f32x4 scq[4] = {};
        __builtin_amdgcn_s_setprio(1);
#pragma unroll
        for (int n = 0; n < 4; ++n) {
            int rbase = (n * 16 + lr) * 128;
#pragma unroll
            for (int c = 0; c < 4; ++c) {
                bf16x8 kf = *(const bf16x8*)&Ks[rbase + ((c * 64 + lk * 16) ^ swz) / 2];
                scq[n] = __builtin_amdgcn_mfma_f32_16x16x32_bf16(qf[c], kf, scq[n], 0, 0, 0);
            }
        }
        __builtin_amdgcn_s_setprio(0);

        bool maskt = (kt == qt);
#pragma unroll
        for (int i = 0; i < 4; ++i) {
            float v0 = scq[0][i], v1 = scq[1][i], v2 = scq[2][i], v3 = scq[3][i];
            if (maskt) {
                int grow = q0 + w * 16 + lk * 4 + i;
                if (k0 + lr > grow)      v0 = -3e38f;
                if (k0 + 16 + lr > grow) v1 = -3e38f;
                if (k0 + 32 + lr > grow) v2 = -3e38f;
                if (k0 + 48 + lr > grow) v3 = -3e38f;
            }
            float mx = fmaxf(fmaxf(v0, v1), fmaxf(v2, v3));
            mx = fmaxf(mx, __shfl_xor(mx, 1));
            mx = fmaxf(mx, __shfl_xor(mx, 2));
            mx = fmaxf(mx, __shfl_xor(mx, 4));
            mx = fmaxf(mx, __shfl_xor(mx, 8));
            if (!__all(mx <= m_i[i] + 8.0f)) {      // defer-max (T13)
                float mnew = fmaxf(m_i[i], mx);
                float a = EXP2F(m_i[i] - mnew);
                l_i[i] *= a;
#pragma unroll
                for (int dt = 0; dt < 8; ++dt) acc[dt][i] *= a;
                m_i[i] = mnew;
            }
            float p0 = EXP2F(v0 - m_i[i]);
            float p1 = EXP2F(v1 - m_i[i]);
            float p2 = EXP2F(v2 - m_i[i]);
            float p3 = EXP2F(v3 - m_i[i]);
            float rs = (p0 + p1) + (p2 + p3);
            rs += __shfl_xor(rs, 1);
            rs += __shfl_xor(rs, 2);
            rs += __shfl_xor(rs, 4);
            rs += __shfl_xor(rs, 8);
            l_i[i] += rs;
            int prow = lk * 4 + i;
            int pz = (prow & 7) << 4;
            bf16_t* pw = Ps[w];
            pw[prow * 64 + ((lr * 2) ^ pz) / 2]       = (bf16_t)p0;
            pw[prow * 64 + ((32 + lr * 2) ^ pz) / 2]  = (bf16_t)p1;
            pw[prow * 64 + ((64 + lr * 2) ^ pz) / 2]  = (bf16_t)p2;
            pw[prow * 64 + ((96 + lr * 2) ^ pz) / 2]  = (bf16_t)p3;
        }

        bf16x8 pf0 = *(const bf16x8*)&Ps[w][lr * 64 + ((lk * 16) ^ swz) / 2];
        bf16x8 pf1 = *(const bf16x8*)&Ps[w][lr * 64 + ((64 + lk * 16) ^ swz) / 2];
        __builtin_amdgcn_s_setprio(1);
#pragma unroll
        for (int dt = 0; dt < 8; ++dt) {
            int vb = (dt * 16 + lr) * 64;
            bf16x8 vf0 = *(const bf16x8*)&Vs[vb + ((lk * 16) ^ swz) / 2];
            acc[dt] = __builtin_amdgcn_mfma_f32_16x16x32_bf16(pf0, vf0, acc[dt], 0, 0, 0);
            bf16x8 vf1 = *(const bf16x8*)&Vs[vb + ((64 + lk * 16) ^ swz) / 2];
            acc[dt] = __builtin_amdgcn_mfma_f32_16x16x32_bf16(pf1, vf1, acc[dt], 0, 0, 0);
        }
        __builtin_amdgcn_s_setprio(0);
        __syncthreads();
    }

#pragma unroll
    for (int i = 0; i < 4; ++i) {
        float rl = 1.0f / l_i[i];
        int s = q0 + w * 16 + lk * 4 + i;
#pragma unroll
        for (int dt = 0; dt < 8; ++dt)
            out[(((size_t)b * S_ + s) * H_ + h) * HD_ + dt * 16 + lr] =
                (bf16_t)(acc[dt][i] * rl);
    }
}

// ---------------------------------------------------------------- launch
extern "C" void kernel_launch(void* const* d_in, const int* in_sizes, int n_in,
                              void* d_out, int out_size, void* d_ws, size_t ws_size,
                              hipStream_t stream) {
    const float* x   = (const float*)d_in[0];
    const float* Wq  = (const float*)d_in[1];
    const float* Wk  = (const float*)d_in[2];
    const float* Wv  = (const float*)d_in[3];
    const float* Wo  = (const float*)d_in[4];
    const float* qnw = (const float*)d_in[5];
    const float* knw = (const float*)d_in[6];
    float* outp = (float*)d_out;

    char* ws = (char*)d_ws;
    size_t off = 0;
    auto alloc = [&](size_t bytes) -> void* {
        void* p = ws + off;
        off += (bytes + 255) & ~(size_t)255;
        return p;
    };
    bf16_t* xb     = (bf16_t*)alloc((size_t)TOK_ * D_ * 2);
    bf16_t* wqb    = (bf16_t*)alloc((size_t)D_ * D_ * 2);
    bf16_t* wkvb   = (bf16_t*)alloc((size_t)D_ * D_ * 2);   // Wk rows then Wv rows
    bf16_t* wob    = (bf16_t*)alloc((size_t)D_ * D_ * 2);
    bf16_t* qproj  = (bf16_t*)alloc((size_t)TOK_ * D_ * 2);
    bf16_t* kvproj = (bf16_t*)alloc((size_t)TOK_ * D_ * 2);
    bf16_t* qhm    = (bf16_t*)alloc((size_t)TOK_ * D_ * 2);
    bf16_t* khm    = (bf16_t*)alloc((size_t)TOK_ * KVH_ * HD_ * 2);
    bf16_t* vtm    = (bf16_t*)alloc((size_t)TOK_ * KVH_ * HD_ * 2);
    bf16_t* attn   = (bf16_t*)alloc((size_t)TOK_ * D_ * 2);
    (void)ws_size; (void)in_sizes; (void)n_in; (void)out_size;

    const int KVSZ = KVH_ * HD_ * D_;
    cvt_bf16<<<(TOK_ * D_) / 1024, 256, 0, stream>>>(x, xb, TOK_ * D_);
    cvt_bf16<<<(D_ * D_) / 1024, 256, 0, stream>>>(Wq, wqb, D_ * D_);
    cvt_bf16<<<KVSZ / 1024, 256, 0, stream>>>(Wk, wkvb, KVSZ);
    cvt_bf16<<<KVSZ / 1024, 256, 0, stream>>>(Wv, wkvb + (size_t)KVSZ, KVSZ);
    cvt_bf16<<<(D_ * D_) / 1024, 256, 0, stream>>>(Wo, wob, D_ * D_);

    // projections (K+V merged into one N=2048 GEMM)
    gemm_bt<bf16_t><<<dim3(D_ / 128, TOK_ / 128), 256, 0, stream>>>(xb, wqb, qproj, TOK_, D_, D_);
    gemm_bt<bf16_t><<<dim3(D_ / 128, TOK_ / 128), 256, 0, stream>>>(xb, wkvb, kvproj, TOK_, D_, D_);

    // norm + rope -> head-major (Q pre-scaled into log2 softmax domain)
    rope_norm<<<(B_ * S_ * H_) / 4, 256, 0, stream>>>(qproj, qnw, qhm, H_, H_, 0, SCALE_LOG2E_);
    rope_norm<<<(B_ * S_ * KVH_) / 4, 256, 0, stream>>>(kvproj, knw, khm, KVH_, H_, 0, 1.0f);

    // V transpose (from merged kvproj, heads 8..15)
    transpose_v<<<dim3(S_ / 32, HD_ / 32, B_ * KVH_), dim3(32, 8), 0, stream>>>(kvproj, vtm);

    // attention
    attn_fwd<<<dim3(S_ / 64, B_ * H_), 256, 0, stream>>>(qhm, khm, vtm, attn);

    // output projection (f32 out)
    gemm_bt<float><<<dim3(D_ / 128, TOK_ / 128), 256, 0, stream>>>(attn, wob, outp, TOK_, D_, D_);
}